// Round 1
// 733.946 us; speedup vs baseline: 1.0057x; 1.0057x over previous
//
#include <hip/hip_runtime.h>
#include <hip/hip_bf16.h>

#define NRES 512
#define DDIM 128
#define HDIM 128
#define NPOS (NRES * NRES)
#define PLANE ((size_t)HDIM * NPOS)
#define EPSF 1e-5f
#define INV_SQRT_N 0.044194173824159216f   // 512^-0.5

typedef __attribute__((ext_vector_type(4))) float  floatx4;
typedef __attribute__((ext_vector_type(8))) short  shortx8;

__device__ __forceinline__ short f2bf(float f) {
    union { float f; unsigned u; } v; v.f = f;
    unsigned r = v.u + 0x7fffu + ((v.u >> 16) & 1u);   // RNE
    return (short)(r >> 16);
}
__device__ __forceinline__ float bf2f(short s) {
    union { unsigned u; float f; } v; v.u = ((unsigned)(unsigned short)s) << 16;
    return v.f;
}

// ---------------------------------------------------------------------------
// Kernel 0: pack projection weights as bf16 in MFMA B-fragment lane order.
// Layout: pair [group(2)][chunk(2)][phase(2:p,g)][ni(4)][ks(4)][lane(64)][8]
//         then w_g  [chunk(2)][ni(4)][ks(4)][lane(64)][8]
// element: h = base + ni*16 + (lane&15), k = ks*32 + (lane>>4)*8 + j
// ---------------------------------------------------------------------------
__global__ __launch_bounds__(256)
void prep_kernel(const float* __restrict__ wabp, const float* __restrict__ wabg,
                 const float* __restrict__ wg, short* __restrict__ wpk)
{
    const int i = blockIdx.x * 256 + threadIdx.x;   // < 81920
    float v;
    if (i < 65536) {
        const int j = i & 7, lane = (i >> 3) & 63, ks = (i >> 9) & 3, ni = (i >> 11) & 3;
        const int phase = (i >> 13) & 1, c = (i >> 14) & 1, grp = (i >> 15) & 1;
        const int h = grp * 128 + c * 64 + ni * 16 + (lane & 15);
        const int k = ks * 32 + ((lane >> 4) & 3) * 8 + j;
        v = (phase ? wabg : wabp)[h * 128 + k];
    } else {
        const int ii = i - 65536;
        const int j = ii & 7, lane = (ii >> 3) & 63, ks = (ii >> 9) & 3, ni = (ii >> 11) & 3;
        const int c = (ii >> 13) & 1;
        const int h = c * 64 + ni * 16 + (lane & 15);
        const int k = ks * 32 + ((lane >> 4) & 3) * 8 + j;
        v = wg[h * 128 + k];
    }
    wpk[i] = f2bf(v);
}

// ---------------------------------------------------------------------------
// Kernel 1 (fused): LayerNorm(z) in-register -> bf16 A-frags, then ALL SIX
// projection chunks for this 128-pos tile (a half0/1, b half0/1, g half0/1).
// One block per pos-tile: z read exactly once from HBM, A-frags reused 6x,
// weights stay L2-resident. Per-row LN closes over the 4 quad-lanes that own
// a row via shfl_xor(16)/shfl_xor(32).
// ---------------------------------------------------------------------------
__global__ __launch_bounds__(256)
void lnproj_kernel(const float* __restrict__ z,
                   const float* __restrict__ lw, const float* __restrict__ lb,
                   const float* __restrict__ mask,
                   const short* __restrict__ wpk,
                   const float* __restrict__ b_ab_p, const float* __restrict__ b_ab_g,
                   float* __restrict__ g_out,
                   short* __restrict__ a_t, short* __restrict__ b_t)
{
    __shared__ short stage[64][136];
    const int tid = threadIdx.x, lane = tid & 63, wave = tid >> 6;
    const int lrow = lane & 15, quad = lane >> 4;
    const int pos0 = blockIdx.x * 128;

    // ---- fused LayerNorm -> A fragments (each lane: rows {mi}, cols ks*32+quad*8..+8)
    shortx8 af[2][4];
    #pragma unroll
    for (int mi = 0; mi < 2; ++mi) {
        const int row = pos0 + wave*32 + mi*16 + lrow;
        const float* zp = z + (size_t)row * DDIM + quad*8;
        float v[4][8];
        float s = 0.f, sq = 0.f;
        #pragma unroll
        for (int ks = 0; ks < 4; ++ks) {
            const float4 v0 = *(const float4*)(zp + ks*32);
            const float4 v1 = *(const float4*)(zp + ks*32 + 4);
            v[ks][0]=v0.x; v[ks][1]=v0.y; v[ks][2]=v0.z; v[ks][3]=v0.w;
            v[ks][4]=v1.x; v[ks][5]=v1.y; v[ks][6]=v1.z; v[ks][7]=v1.w;
            s  += v0.x+v0.y+v0.z+v0.w + v1.x+v1.y+v1.z+v1.w;
            sq += v0.x*v0.x+v0.y*v0.y+v0.z*v0.z+v0.w*v0.w
                + v1.x*v1.x+v1.y*v1.y+v1.z*v1.z+v1.w*v1.w;
        }
        // sum across the 4 quad-lanes that hold this row (lane ^ 16, ^ 32)
        s  += __shfl_xor(s, 16);  sq += __shfl_xor(sq, 16);
        s  += __shfl_xor(s, 32);  sq += __shfl_xor(sq, 32);
        const float mean = s * (1.f/128.f);
        const float var  = sq * (1.f/128.f) - mean * mean;
        const float inv  = rsqrtf(var + EPSF);
        #pragma unroll
        for (int ks = 0; ks < 4; ++ks) {
            const int cb = ks*32 + quad*8;
            shortx8 o;
            #pragma unroll
            for (int j = 0; j < 8; ++j)
                o[j] = f2bf((v[ks][j] - mean) * inv * lw[cb+j] + lb[cb+j]);
            af[mi][ks] = o;
        }
    }

    // mask rows this lane's accumulators cover (same for every chunk)
    float mv[2][4];
    #pragma unroll
    for (int mi = 0; mi < 2; ++mi)
        #pragma unroll
        for (int r = 0; r < 4; ++r)
            mv[mi][r] = mask[pos0 + wave*32 + mi*16 + quad*4 + r] * INV_SQRT_N;

    // ---- chunks 0..3: a (h 0-63 / 64-127), b (h 0-63 / 64-127)
    #pragma unroll 1
    for (int chunk = 0; chunk < 4; ++chunk) {
        const int grp = chunk >> 1, c = chunk & 1;
        const short* pb = wpk + (size_t)(chunk*2    ) * 8192 + lane*8;
        const short* gb = wpk + (size_t)(chunk*2 + 1) * 8192 + lane*8;
        floatx4 accp[2][4], accg[2][4];
        #pragma unroll
        for (int mi = 0; mi < 2; ++mi)
            #pragma unroll
            for (int ni = 0; ni < 4; ++ni) {
                accp[mi][ni] = (floatx4){0.f,0.f,0.f,0.f};
                accg[mi][ni] = (floatx4){0.f,0.f,0.f,0.f};
            }
        #pragma unroll
        for (int ks = 0; ks < 4; ++ks)
            #pragma unroll
            for (int ni = 0; ni < 4; ++ni) {
                shortx8 bp = *(const shortx8*)(pb + (ni*4 + ks)*512);
                accp[0][ni] = __builtin_amdgcn_mfma_f32_16x16x32_bf16(af[0][ks], bp, accp[0][ni], 0,0,0);
                accp[1][ni] = __builtin_amdgcn_mfma_f32_16x16x32_bf16(af[1][ks], bp, accp[1][ni], 0,0,0);
                shortx8 bg = *(const shortx8*)(gb + (ni*4 + ks)*512);
                accg[0][ni] = __builtin_amdgcn_mfma_f32_16x16x32_bf16(af[0][ks], bg, accg[0][ni], 0,0,0);
                accg[1][ni] = __builtin_amdgcn_mfma_f32_16x16x32_bf16(af[1][ks], bg, accg[1][ni], 0,0,0);
            }
        const int hb0 = grp*128 + c*64;
        __syncthreads();   // stage free (previous chunk's readers done)
        #pragma unroll
        for (int mi = 0; mi < 2; ++mi)
            #pragma unroll
            for (int ni = 0; ni < 4; ++ni) {
                const int col = ni*16 + lrow;
                const float bp = b_ab_p[hb0 + col];
                const float bg = b_ab_g[hb0 + col];
                #pragma unroll
                for (int r = 0; r < 4; ++r) {
                    const int row = wave*32 + mi*16 + quad*4 + r;
                    const float sig = 1.f / (1.f + __expf(-(accg[mi][ni][r] + bg)));
                    stage[col][row] = f2bf((accp[mi][ni][r] + bp) * sig * mv[mi][r]);
                }
            }
        __syncthreads();
        short* dst = ((grp == 0) ? a_t : b_t)
                   + (size_t)(c*64 + (tid >> 2)) * NPOS + pos0 + (tid & 3) * 32;
        const short* sp = &stage[tid >> 2][(tid & 3) * 32];
        #pragma unroll
        for (int q = 0; q < 4; ++q)
            ((int4*)dst)[q] = ((const int4*)sp)[q];
    }

    // ---- chunks 4..5: gate logits g = zl . w_g^T (fp32 out, no LDS needed)
    #pragma unroll 1
    for (int c = 0; c < 2; ++c) {
        const short* gg = wpk + 65536 + (size_t)c * 8192 + lane*8;
        floatx4 acc[2][4];
        #pragma unroll
        for (int mi = 0; mi < 2; ++mi)
            #pragma unroll
            for (int ni = 0; ni < 4; ++ni)
                acc[mi][ni] = (floatx4){0.f,0.f,0.f,0.f};
        #pragma unroll
        for (int ks = 0; ks < 4; ++ks)
            #pragma unroll
            for (int ni = 0; ni < 4; ++ni) {
                shortx8 bw = *(const shortx8*)(gg + (ni*4 + ks)*512);
                acc[0][ni] = __builtin_amdgcn_mfma_f32_16x16x32_bf16(af[0][ks], bw, acc[0][ni], 0,0,0);
                acc[1][ni] = __builtin_amdgcn_mfma_f32_16x16x32_bf16(af[1][ks], bw, acc[1][ni], 0,0,0);
            }
        #pragma unroll
        for (int mi = 0; mi < 2; ++mi)
            #pragma unroll
            for (int ni = 0; ni < 4; ++ni)
                #pragma unroll
                for (int r = 0; r < 4; ++r) {
                    const int row = wave*32 + mi*16 + quad*4 + r;
                    g_out[(size_t)(pos0 + row) * DDIM + c*64 + ni*16 + lrow] = acc[mi][ni][r];
                }
    }
}

// ---------------------------------------------------------------------------
// Kernel 3: triangle einsum — round-1-verbatim proven version.
// 128 batched per-h GEMMs, C = A * B^T, K=512, padded LDS vector staging.
// ---------------------------------------------------------------------------
__global__ __launch_bounds__(256)
void tri_kernel(const short* __restrict__ a_t, const short* __restrict__ b_t,
                short* __restrict__ xr)
{
    __shared__ short As[128][72];   // BK=64, row stride 144B (16B mult)
    __shared__ short Bs[128][72];

    const int tid  = threadIdx.x;
    const int lane = tid & 63;
    const int wave = tid >> 6;
    const int i0 = blockIdx.x * 128;
    const int j0 = blockIdx.y * 128;
    const int h  = blockIdx.z;
    const short* A = a_t + (size_t)h * NPOS;
    const short* B = b_t + (size_t)h * NPOS;

    floatx4 acc[2][8];
    #pragma unroll
    for (int mi = 0; mi < 2; ++mi)
        #pragma unroll
        for (int ni = 0; ni < 8; ++ni)
            acc[mi][ni] = (floatx4){0.f, 0.f, 0.f, 0.f};

    const int lr = tid >> 1;
    const int lh = tid & 1;
    const int lrow = lane & 15;
    const int quad = lane >> 4;

    for (int k0 = 0; k0 < NRES; k0 += 64) {
        const short* pa = A + (size_t)(i0 + lr) * NRES + k0 + lh * 32;
        const short* pb = B + (size_t)(j0 + lr) * NRES + k0 + lh * 32;
        #pragma unroll
        for (int c = 0; c < 4; ++c) {
            *(int4*)&As[lr][lh*32 + c*8] = ((const int4*)pa)[c];
            *(int4*)&Bs[lr][lh*32 + c*8] = ((const int4*)pb)[c];
        }
        __syncthreads();
        #pragma unroll
        for (int ks = 0; ks < 2; ++ks) {
            shortx8 af0 = *(const shortx8*)&As[wave*32      + lrow][ks*32 + quad*8];
            shortx8 af1 = *(const shortx8*)&As[wave*32 + 16 + lrow][ks*32 + quad*8];
            #pragma unroll
            for (int ni = 0; ni < 8; ++ni) {
                shortx8 bf = *(const shortx8*)&Bs[ni*16 + lrow][ks*32 + quad*8];
                acc[0][ni] = __builtin_amdgcn_mfma_f32_16x16x32_bf16(af0, bf, acc[0][ni], 0, 0, 0);
                acc[1][ni] = __builtin_amdgcn_mfma_f32_16x16x32_bf16(af1, bf, acc[1][ni], 0, 0, 0);
            }
        }
        __syncthreads();
    }

    short* xp = xr + (size_t)h * NPOS;
    #pragma unroll
    for (int mi = 0; mi < 2; ++mi)
        #pragma unroll
        for (int ni = 0; ni < 8; ++ni)
            #pragma unroll
            for (int r = 0; r < 4; ++r) {
                const int row = wave*32 + mi*16 + quad*4 + r;
                const int col = ni*16 + lrow;
                xp[(size_t)(i0 + row) * NRES + j0 + col] = f2bf(acc[mi][ni][r]);
            }
}

// ---------------------------------------------------------------------------
// Kernel 4: gather h-planes for a 128-pos tile, LN over h, project with w_z.
// ---------------------------------------------------------------------------
__global__ __launch_bounds__(256)
void out_kernel(const short* __restrict__ xr,
                const float* __restrict__ ln_w, const float* __restrict__ ln_b,
                const float* __restrict__ w_z, float* __restrict__ x_out)
{
    __shared__ float xt[128][130];    // [h][pos] fp32
    __shared__ short xln[128][136];   // [pos][h] bf16 (MFMA A tile)
    __shared__ short Bw[128][136];    // w_z bf16 [d][h]
    __shared__ float red_s[2][128];
    __shared__ float red_q[2][128];
    __shared__ float mean_l[128];
    __shared__ float inv_l[128];

    const int tid  = threadIdx.x;
    const int lane = tid & 63;
    const int wave = tid >> 6;
    const int pos0 = blockIdx.x * 128;

    {
        const int hr = tid >> 1;
        const int hf = tid & 1;
        const short* sp = xr + (size_t)hr * NPOS + pos0 + hf * 64;
        #pragma unroll
        for (int c = 0; c < 8; ++c) {
            shortx8 v = ((const shortx8*)sp)[c];
            #pragma unroll
            for (int j = 0; j < 8; ++j)
                xt[hr][hf*64 + c*8 + j] = bf2f(v[j]);
        }
        const float* wp = w_z + (size_t)hr * HDIM + hf * 64;
        #pragma unroll
        for (int c = 0; c < 16; ++c) {
            float4 v = ((const float4*)wp)[c];
            short4 o;
            o.x = f2bf(v.x); o.y = f2bf(v.y); o.z = f2bf(v.z); o.w = f2bf(v.w);
            *(short4*)&Bw[hr][hf*64 + c*4] = o;
        }
    }
    __syncthreads();

    {
        const int p  = tid & 127;
        const int hf = tid >> 7;
        float s = 0.f, sq = 0.f;
        for (int hh = hf*64; hh < hf*64 + 64; ++hh) {
            const float v = xt[hh][p];
            s += v; sq += v * v;
        }
        red_s[hf][p] = s;
        red_q[hf][p] = sq;
    }
    __syncthreads();
    if (tid < 128) {
        const float s  = red_s[0][tid] + red_s[1][tid];
        const float sq = red_q[0][tid] + red_q[1][tid];
        const float mean = s * (1.f/128.f);
        const float var  = sq * (1.f/128.f) - mean * mean;
        mean_l[tid] = mean;
        inv_l[tid]  = rsqrtf(var + EPSF);
    }
    __syncthreads();

    {
        const int p  = tid & 127;
        const int hf = tid >> 7;
        const float mean = mean_l[p];
        const float inv  = inv_l[p];
        for (int hh = hf*64; hh < hf*64 + 64; hh += 2) {
            short2 o;
            o.x = f2bf((xt[hh  ][p] - mean) * inv * ln_w[hh  ] + ln_b[hh  ]);
            o.y = f2bf((xt[hh+1][p] - mean) * inv * ln_w[hh+1] + ln_b[hh+1]);
            *(short2*)&xln[p][hh] = o;
        }
    }
    __syncthreads();

    floatx4 acc[2][8];
    #pragma unroll
    for (int mi = 0; mi < 2; ++mi)
        #pragma unroll
        for (int ni = 0; ni < 8; ++ni)
            acc[mi][ni] = (floatx4){0.f,0.f,0.f,0.f};

    const int lrow = lane & 15;
    const int quad = lane >> 4;
    #pragma unroll
    for (int ks = 0; ks < 4; ++ks) {
        shortx8 af0 = *(const shortx8*)&xln[wave*32      + lrow][ks*32 + quad*8];
        shortx8 af1 = *(const shortx8*)&xln[wave*32 + 16 + lrow][ks*32 + quad*8];
        #pragma unroll
        for (int ni = 0; ni < 8; ++ni) {
            shortx8 bf = *(const shortx8*)&Bw[ni*16 + lrow][ks*32 + quad*8];
            acc[0][ni] = __builtin_amdgcn_mfma_f32_16x16x32_bf16(af0, bf, acc[0][ni], 0,0,0);
            acc[1][ni] = __builtin_amdgcn_mfma_f32_16x16x32_bf16(af1, bf, acc[1][ni], 0,0,0);
        }
    }
    #pragma unroll
    for (int mi = 0; mi < 2; ++mi)
        #pragma unroll
        for (int ni = 0; ni < 8; ++ni)
            #pragma unroll
            for (int r = 0; r < 4; ++r) {
                const int row = wave*32 + mi*16 + quad*4 + r;
                const int col = ni*16 + lrow;
                x_out[(size_t)(pos0 + row) * DDIM + col] = acc[mi][ni][r];
            }
}

extern "C" void kernel_launch(void* const* d_in, const int* in_sizes, int n_in,
                              void* d_out, int out_size, void* d_ws, size_t ws_size,
                              hipStream_t stream)
{
    const float* z        = (const float*)d_in[0];
    const float* mask     = (const float*)d_in[1];
    const float* ln_in_w  = (const float*)d_in[2];
    const float* ln_in_b  = (const float*)d_in[3];
    const float* w_ab_p   = (const float*)d_in[4];
    const float* b_ab_p   = (const float*)d_in[5];
    const float* w_ab_g   = (const float*)d_in[6];
    const float* b_ab_g   = (const float*)d_in[7];
    const float* w_g      = (const float*)d_in[8];
    const float* ln_out_w = (const float*)d_in[9];
    const float* ln_out_b = (const float*)d_in[10];
    const float* w_z      = (const float*)d_in[11];

    float* x_out = (float*)d_out;
    float* g_out = x_out + (size_t)NPOS * DDIM;

    // ws: a_t | b_t | xr  (zl no longer exists — LN is fused into proj)
    short* a_t = (short*)d_ws;
    short* b_t = a_t + PLANE;
    short* xr  = b_t + PLANE;
    // packed bf16 weights live in the x-output region of d_out until out_kernel
    // overwrites it (prep -> lnproj ordering is stream-serialized).
    short* wpk = (short*)x_out;

    prep_kernel<<<320, 256, 0, stream>>>(w_ab_p, w_ab_g, w_g, wpk);
    lnproj_kernel<<<NPOS/128, 256, 0, stream>>>(z, ln_in_w, ln_in_b, mask, wpk,
                                                b_ab_p, b_ab_g,
                                                g_out, a_t, b_t);
    tri_kernel<<<dim3(4, 4, 128), 256, 0, stream>>>(a_t, b_t, xr);
    out_kernel<<<NPOS/128, 256, 0, stream>>>(xr, ln_out_w, ln_out_b, w_z, x_out);
}

// Round 3
// 684.644 us; speedup vs baseline: 1.0782x; 1.0720x over previous
//
#include <hip/hip_runtime.h>
#include <hip/hip_bf16.h>

#define NRES 512
#define DDIM 128
#define HDIM 128
#define NPOS (NRES * NRES)
#define PLANE ((size_t)HDIM * NPOS)
#define EPSF 1e-5f
#define INV_SQRT_N 0.044194173824159216f   // 512^-0.5

typedef __attribute__((ext_vector_type(4))) float  floatx4;
typedef __attribute__((ext_vector_type(8))) short  shortx8;

__device__ __forceinline__ short f2bf(float f) {
    union { float f; unsigned u; } v; v.f = f;
    unsigned r = v.u + 0x7fffu + ((v.u >> 16) & 1u);   // RNE
    return (short)(r >> 16);
}
__device__ __forceinline__ float bf2f(short s) {
    union { unsigned u; float f; } v; v.u = ((unsigned)(unsigned short)s) << 16;
    return v.f;
}

// HBM -> LDS direct DMA, 16B per lane. LDS dest is wave-uniform base + lane*16
// (m104 semantics); global src is per-lane. Integer round-trip for the
// address-space casts (CK's amd_direct_load pattern; the shared aperture is
// 4GB-aligned so the low 32 bits of a flat LDS pointer are the LDS offset).
__device__ __forceinline__ void g2lds16(const short* gp, short* lp) {
    const unsigned __attribute__((address_space(1)))* g =
        (const unsigned __attribute__((address_space(1)))*)(unsigned long long)(uintptr_t)gp;
    unsigned __attribute__((address_space(3)))* l =
        (unsigned __attribute__((address_space(3)))*)(unsigned)(uintptr_t)lp;
    __builtin_amdgcn_global_load_lds(g, l, 16, 0, 0);
}

// ---------------------------------------------------------------------------
// Kernel 0: pack projection weights as bf16 in MFMA B-fragment lane order.
// Layout: pair [group(2)][chunk(2)][phase(2:p,g)][ni(4)][ks(4)][lane(64)][8]
//         then w_g  [chunk(2)][ni(4)][ks(4)][lane(64)][8]
// element: h = base + ni*16 + (lane&15), k = ks*32 + (lane>>4)*8 + j
// ---------------------------------------------------------------------------
__global__ __launch_bounds__(256)
void prep_kernel(const float* __restrict__ wabp, const float* __restrict__ wabg,
                 const float* __restrict__ wg, short* __restrict__ wpk)
{
    const int i = blockIdx.x * 256 + threadIdx.x;   // < 81920
    float v;
    if (i < 65536) {
        const int j = i & 7, lane = (i >> 3) & 63, ks = (i >> 9) & 3, ni = (i >> 11) & 3;
        const int phase = (i >> 13) & 1, c = (i >> 14) & 1, grp = (i >> 15) & 1;
        const int h = grp * 128 + c * 64 + ni * 16 + (lane & 15);
        const int k = ks * 32 + ((lane >> 4) & 3) * 8 + j;
        v = (phase ? wabg : wabp)[h * 128 + k];
    } else {
        const int ii = i - 65536;
        const int j = ii & 7, lane = (ii >> 3) & 63, ks = (ii >> 9) & 3, ni = (ii >> 11) & 3;
        const int c = (ii >> 13) & 1;
        const int h = c * 64 + ni * 16 + (lane & 15);
        const int k = ks * 32 + ((lane >> 4) & 3) * 8 + j;
        v = wg[h * 128 + k];
    }
    wpk[i] = f2bf(v);
}

// ---------------------------------------------------------------------------
// Kernel 0b: pack w_z [d][h] as bf16 MFMA B-frags: [ni(8)][ks(4)][lane(64)][8]
// d = ni*16 + (lane&15), h = ks*32 + (lane>>4)*8 + j.  16384 shorts.
// Runs AFTER tri (target region aliases dead a_t).
// ---------------------------------------------------------------------------
__global__ __launch_bounds__(256)
void prep_wz_kernel(const float* __restrict__ wz, short* __restrict__ wzpk)
{
    const int i = blockIdx.x * 256 + threadIdx.x;   // < 16384
    const int j = i & 7, lane = (i >> 3) & 63, ks = (i >> 9) & 3, ni = (i >> 11) & 7;
    const int d = ni * 16 + (lane & 15);
    const int h = ks * 32 + ((lane >> 4) & 3) * 8 + j;
    wzpk[i] = f2bf(wz[d * 128 + h]);
}

// ---------------------------------------------------------------------------
// Kernel 1 (fused): LayerNorm(z) in-register -> bf16 A-frags, then ALL SIX
// projection chunks for this 128-pos tile. (unchanged — proven in round 1)
// ---------------------------------------------------------------------------
__global__ __launch_bounds__(256)
void lnproj_kernel(const float* __restrict__ z,
                   const float* __restrict__ lw, const float* __restrict__ lb,
                   const float* __restrict__ mask,
                   const short* __restrict__ wpk,
                   const float* __restrict__ b_ab_p, const float* __restrict__ b_ab_g,
                   float* __restrict__ g_out,
                   short* __restrict__ a_t, short* __restrict__ b_t)
{
    __shared__ short stage[64][136];
    const int tid = threadIdx.x, lane = tid & 63, wave = tid >> 6;
    const int lrow = lane & 15, quad = lane >> 4;
    const int pos0 = blockIdx.x * 128;

    shortx8 af[2][4];
    #pragma unroll
    for (int mi = 0; mi < 2; ++mi) {
        const int row = pos0 + wave*32 + mi*16 + lrow;
        const float* zp = z + (size_t)row * DDIM + quad*8;
        float v[4][8];
        float s = 0.f, sq = 0.f;
        #pragma unroll
        for (int ks = 0; ks < 4; ++ks) {
            const float4 v0 = *(const float4*)(zp + ks*32);
            const float4 v1 = *(const float4*)(zp + ks*32 + 4);
            v[ks][0]=v0.x; v[ks][1]=v0.y; v[ks][2]=v0.z; v[ks][3]=v0.w;
            v[ks][4]=v1.x; v[ks][5]=v1.y; v[ks][6]=v1.z; v[ks][7]=v1.w;
            s  += v0.x+v0.y+v0.z+v0.w + v1.x+v1.y+v1.z+v1.w;
            sq += v0.x*v0.x+v0.y*v0.y+v0.z*v0.z+v0.w*v0.w
                + v1.x*v1.x+v1.y*v1.y+v1.z*v1.z+v1.w*v1.w;
        }
        s  += __shfl_xor(s, 16);  sq += __shfl_xor(sq, 16);
        s  += __shfl_xor(s, 32);  sq += __shfl_xor(sq, 32);
        const float mean = s * (1.f/128.f);
        const float var  = sq * (1.f/128.f) - mean * mean;
        const float inv  = rsqrtf(var + EPSF);
        #pragma unroll
        for (int ks = 0; ks < 4; ++ks) {
            const int cb = ks*32 + quad*8;
            shortx8 o;
            #pragma unroll
            for (int j = 0; j < 8; ++j)
                o[j] = f2bf((v[ks][j] - mean) * inv * lw[cb+j] + lb[cb+j]);
            af[mi][ks] = o;
        }
    }

    float mv[2][4];
    #pragma unroll
    for (int mi = 0; mi < 2; ++mi)
        #pragma unroll
        for (int r = 0; r < 4; ++r)
            mv[mi][r] = mask[pos0 + wave*32 + mi*16 + quad*4 + r] * INV_SQRT_N;

    #pragma unroll 1
    for (int chunk = 0; chunk < 4; ++chunk) {
        const int grp = chunk >> 1, c = chunk & 1;
        const short* pb = wpk + (size_t)(chunk*2    ) * 8192 + lane*8;
        const short* gb = wpk + (size_t)(chunk*2 + 1) * 8192 + lane*8;
        floatx4 accp[2][4], accg[2][4];
        #pragma unroll
        for (int mi = 0; mi < 2; ++mi)
            #pragma unroll
            for (int ni = 0; ni < 4; ++ni) {
                accp[mi][ni] = (floatx4){0.f,0.f,0.f,0.f};
                accg[mi][ni] = (floatx4){0.f,0.f,0.f,0.f};
            }
        #pragma unroll
        for (int ks = 0; ks < 4; ++ks)
            #pragma unroll
            for (int ni = 0; ni < 4; ++ni) {
                shortx8 bp = *(const shortx8*)(pb + (ni*4 + ks)*512);
                accp[0][ni] = __builtin_amdgcn_mfma_f32_16x16x32_bf16(af[0][ks], bp, accp[0][ni], 0,0,0);
                accp[1][ni] = __builtin_amdgcn_mfma_f32_16x16x32_bf16(af[1][ks], bp, accp[1][ni], 0,0,0);
                shortx8 bg = *(const shortx8*)(gb + (ni*4 + ks)*512);
                accg[0][ni] = __builtin_amdgcn_mfma_f32_16x16x32_bf16(af[0][ks], bg, accg[0][ni], 0,0,0);
                accg[1][ni] = __builtin_amdgcn_mfma_f32_16x16x32_bf16(af[1][ks], bg, accg[1][ni], 0,0,0);
            }
        const int hb0 = grp*128 + c*64;
        __syncthreads();
        #pragma unroll
        for (int mi = 0; mi < 2; ++mi)
            #pragma unroll
            for (int ni = 0; ni < 4; ++ni) {
                const int col = ni*16 + lrow;
                const float bp = b_ab_p[hb0 + col];
                const float bg = b_ab_g[hb0 + col];
                #pragma unroll
                for (int r = 0; r < 4; ++r) {
                    const int row = wave*32 + mi*16 + quad*4 + r;
                    const float sig = 1.f / (1.f + __expf(-(accg[mi][ni][r] + bg)));
                    stage[col][row] = f2bf((accp[mi][ni][r] + bp) * sig * mv[mi][r]);
                }
            }
        __syncthreads();
        short* dst = ((grp == 0) ? a_t : b_t)
                   + (size_t)(c*64 + (tid >> 2)) * NPOS + pos0 + (tid & 3) * 32;
        const short* sp = &stage[tid >> 2][(tid & 3) * 32];
        #pragma unroll
        for (int q = 0; q < 4; ++q)
            ((int4*)dst)[q] = ((const int4*)sp)[q];
    }

    #pragma unroll 1
    for (int c = 0; c < 2; ++c) {
        const short* gg = wpk + 65536 + (size_t)c * 8192 + lane*8;
        floatx4 acc[2][4];
        #pragma unroll
        for (int mi = 0; mi < 2; ++mi)
            #pragma unroll
            for (int ni = 0; ni < 4; ++ni)
                acc[mi][ni] = (floatx4){0.f,0.f,0.f,0.f};
        #pragma unroll
        for (int ks = 0; ks < 4; ++ks)
            #pragma unroll
            for (int ni = 0; ni < 4; ++ni) {
                shortx8 bw = *(const shortx8*)(gg + (ni*4 + ks)*512);
                acc[0][ni] = __builtin_amdgcn_mfma_f32_16x16x32_bf16(af[0][ks], bw, acc[0][ni], 0,0,0);
                acc[1][ni] = __builtin_amdgcn_mfma_f32_16x16x32_bf16(af[1][ks], bw, acc[1][ni], 0,0,0);
            }
        #pragma unroll
        for (int mi = 0; mi < 2; ++mi)
            #pragma unroll
            for (int ni = 0; ni < 4; ++ni)
                #pragma unroll
                for (int r = 0; r < 4; ++r) {
                    const int row = wave*32 + mi*16 + quad*4 + r;
                    g_out[(size_t)(pos0 + row) * DDIM + c*64 + ni*16 + lrow] = acc[mi][ni][r];
                }
    }
}

// ---------------------------------------------------------------------------
// Kernel 3: triangle einsum, v2 — global_load_lds dwordx4 staging (m97 lever),
// linear [128][64] LDS (T2 null at 128^2 + 2-phase per m228d), same MFMA body.
// ---------------------------------------------------------------------------
__global__ __launch_bounds__(256)
void tri_kernel(const short* __restrict__ a_t, const short* __restrict__ b_t,
                short* __restrict__ xr)
{
    __shared__ short As[128 * 64];   // linear: row*64 + k (16 KB)
    __shared__ short Bs[128 * 64];

    const int tid  = threadIdx.x;
    const int lane = tid & 63;
    const int wave = tid >> 6;
    const int i0 = blockIdx.x * 128;
    const int j0 = blockIdx.y * 128;
    const int h  = blockIdx.z;
    const short* A = a_t + (size_t)h * NPOS;
    const short* B = b_t + (size_t)h * NPOS;

    floatx4 acc[2][8];
    #pragma unroll
    for (int mi = 0; mi < 2; ++mi)
        #pragma unroll
        for (int ni = 0; ni < 8; ++ni)
            acc[mi][ni] = (floatx4){0.f, 0.f, 0.f, 0.f};

    const int lrow = lane & 15;
    const int quad = lane >> 4;
    // staging geometry: call c stages rows c*32+wave*8 .. +8; lane l covers
    // row offset l>>3, 16B col block l&7. LDS dest = linear base + lane*16.
    const int srow = wave*8 + (lane >> 3);        // 0..31 within call-c group
    const int scol = (lane & 7) * 8;              // shorts
    const short* pa = A + (size_t)(i0 + srow) * NRES + scol;
    const short* pb = B + (size_t)(j0 + srow) * NRES + scol;

    for (int k0 = 0; k0 < NRES; k0 += 64) {
        #pragma unroll
        for (int c = 0; c < 4; ++c) {
            g2lds16(pa + (size_t)c*32*NRES + k0, &As[(c*32 + wave*8) * 64]);
            g2lds16(pb + (size_t)c*32*NRES + k0, &Bs[(c*32 + wave*8) * 64]);
        }
        __syncthreads();   // compiler drains vmcnt before s_barrier
        #pragma unroll
        for (int ks = 0; ks < 2; ++ks) {
            shortx8 af0 = *(const shortx8*)&As[(wave*32      + lrow)*64 + ks*32 + quad*8];
            shortx8 af1 = *(const shortx8*)&As[(wave*32 + 16 + lrow)*64 + ks*32 + quad*8];
            #pragma unroll
            for (int ni = 0; ni < 8; ++ni) {
                shortx8 bf = *(const shortx8*)&Bs[(ni*16 + lrow)*64 + ks*32 + quad*8];
                acc[0][ni] = __builtin_amdgcn_mfma_f32_16x16x32_bf16(af0, bf, acc[0][ni], 0, 0, 0);
                acc[1][ni] = __builtin_amdgcn_mfma_f32_16x16x32_bf16(af1, bf, acc[1][ni], 0, 0, 0);
            }
        }
        __syncthreads();
    }

    short* xp = xr + (size_t)h * NPOS;
    #pragma unroll
    for (int mi = 0; mi < 2; ++mi)
        #pragma unroll
        for (int ni = 0; ni < 8; ++ni)
            #pragma unroll
            for (int r = 0; r < 4; ++r) {
                const int row = wave*32 + mi*16 + quad*4 + r;
                const int col = ni*16 + lrow;
                xp[(size_t)(i0 + row) * NRES + j0 + col] = f2bf(acc[mi][ni][r]);
            }
}

// ---------------------------------------------------------------------------
// Kernel 4 v2: gather h-planes (bf16, no fp32 expansion), LN over h, project
// with pre-packed w_z frags from global (L2-resident). LDS 139 KB -> 72.7 KB
// => 2 blocks/CU.  (round-2 gather bug fixed: 8 int4 = 64 shorts per thread)
// ---------------------------------------------------------------------------
__global__ __launch_bounds__(256)
void out_kernel(const short* __restrict__ xr,
                const float* __restrict__ ln_w, const float* __restrict__ ln_b,
                const short* __restrict__ wzpk, float* __restrict__ x_out)
{
    __shared__ short X[128][136];     // [h][pos] bf16
    __shared__ short xln[128][136];   // [pos][h] bf16 (MFMA A tile)
    __shared__ float red_s[2][128];
    __shared__ float red_q[2][128];
    __shared__ float mean_l[128];
    __shared__ float inv_l[128];

    const int tid  = threadIdx.x;
    const int lane = tid & 63;
    const int wave = tid >> 6;
    const int pos0 = blockIdx.x * 128;

    {   // gather: straight bf16 copy, 128B per thread (8 x int4)
        const int hr = tid >> 1;
        const int hf = tid & 1;
        const short* sp = xr + (size_t)hr * NPOS + pos0 + hf * 64;
        #pragma unroll
        for (int c = 0; c < 8; ++c)
            *(int4*)&X[hr][hf*64 + c*8] = ((const int4*)sp)[c];
    }
    __syncthreads();

    {   // per-position sums over h (column walk, 2 lanes/bank = free)
        const int p  = tid & 127;
        const int hf = tid >> 7;
        float s = 0.f, sq = 0.f;
        #pragma unroll
        for (int hh = hf*64; hh < hf*64 + 64; ++hh) {
            const float v = bf2f(X[hh][p]);
            s += v; sq += v * v;
        }
        red_s[hf][p] = s;
        red_q[hf][p] = sq;
    }
    __syncthreads();
    if (tid < 128) {
        const float s  = red_s[0][tid] + red_s[1][tid];
        const float sq = red_q[0][tid] + red_q[1][tid];
        const float mean = s * (1.f/128.f);
        const float var  = sq * (1.f/128.f) - mean * mean;
        mean_l[tid] = mean;
        inv_l[tid]  = rsqrtf(var + EPSF);
    }
    __syncthreads();

    {   // normalize + transpose into xln[pos][h]
        const int p  = tid & 127;
        const int hf = tid >> 7;
        const float mean = mean_l[p];
        const float inv  = inv_l[p];
        #pragma unroll
        for (int hh = hf*64; hh < hf*64 + 64; hh += 2) {
            short2 o;
            o.x = f2bf((bf2f(X[hh  ][p]) - mean) * inv * ln_w[hh  ] + ln_b[hh  ]);
            o.y = f2bf((bf2f(X[hh+1][p]) - mean) * inv * ln_w[hh+1] + ln_b[hh+1]);
            *(short2*)&xln[p][hh] = o;
        }
    }
    __syncthreads();

    floatx4 acc[2][8];
    #pragma unroll
    for (int mi = 0; mi < 2; ++mi)
        #pragma unroll
        for (int ni = 0; ni < 8; ++ni)
            acc[mi][ni] = (floatx4){0.f,0.f,0.f,0.f};

    const int lrow = lane & 15;
    const int quad = lane >> 4;
    const short* gb = wzpk + lane*8;
    #pragma unroll
    for (int ks = 0; ks < 4; ++ks) {
        shortx8 af0 = *(const shortx8*)&xln[wave*32      + lrow][ks*32 + quad*8];
        shortx8 af1 = *(const shortx8*)&xln[wave*32 + 16 + lrow][ks*32 + quad*8];
        #pragma unroll
        for (int ni = 0; ni < 8; ++ni) {
            shortx8 bf = *(const shortx8*)(gb + (ni*4 + ks)*512);
            acc[0][ni] = __builtin_amdgcn_mfma_f32_16x16x32_bf16(af0, bf, acc[0][ni], 0,0,0);
            acc[1][ni] = __builtin_amdgcn_mfma_f32_16x16x32_bf16(af1, bf, acc[1][ni], 0,0,0);
        }
    }
    #pragma unroll
    for (int mi = 0; mi < 2; ++mi)
        #pragma unroll
        for (int ni = 0; ni < 8; ++ni)
            #pragma unroll
            for (int r = 0; r < 4; ++r) {
                const int row = wave*32 + mi*16 + quad*4 + r;
                const int col = ni*16 + lrow;
                x_out[(size_t)(pos0 + row) * DDIM + col] = acc[mi][ni][r];
            }
}

extern "C" void kernel_launch(void* const* d_in, const int* in_sizes, int n_in,
                              void* d_out, int out_size, void* d_ws, size_t ws_size,
                              hipStream_t stream)
{
    const float* z        = (const float*)d_in[0];
    const float* mask     = (const float*)d_in[1];
    const float* ln_in_w  = (const float*)d_in[2];
    const float* ln_in_b  = (const float*)d_in[3];
    const float* w_ab_p   = (const float*)d_in[4];
    const float* b_ab_p   = (const float*)d_in[5];
    const float* w_ab_g   = (const float*)d_in[6];
    const float* b_ab_g   = (const float*)d_in[7];
    const float* w_g      = (const float*)d_in[8];
    const float* ln_out_w = (const float*)d_in[9];
    const float* ln_out_b = (const float*)d_in[10];
    const float* w_z      = (const float*)d_in[11];

    float* x_out = (float*)d_out;
    float* g_out = x_out + (size_t)NPOS * DDIM;

    // ws: a_t | b_t | xr
    short* a_t = (short*)d_ws;
    short* b_t = a_t + PLANE;
    short* xr  = b_t + PLANE;
    // ab/g packed weights alias x_out (dead before out_kernel writes x_out).
    short* wpk = (short*)x_out;
    // w_z packed frags alias a_t (dead after tri; prep_wz runs after tri).
    short* wzpk = a_t;

    prep_kernel<<<320, 256, 0, stream>>>(w_ab_p, w_ab_g, w_g, wpk);
    lnproj_kernel<<<NPOS/128, 256, 0, stream>>>(z, ln_in_w, ln_in_b, mask, wpk,
                                                b_ab_p, b_ab_g,
                                                g_out, a_t, b_t);
    tri_kernel<<<dim3(4, 4, 128), 256, 0, stream>>>(a_t, b_t, xr);
    prep_wz_kernel<<<64, 256, 0, stream>>>(w_z, wzpk);
    out_kernel<<<NPOS/128, 256, 0, stream>>>(xr, ln_out_w, ln_out_b, wzpk, x_out);
}